// Round 12
// baseline (22.133 us; speedup 1.0000x reference)
//
#include <hip/hip_runtime.h>

// out[b] = SCALE^2 * ( dot(x[b,:], colsum) + sum(bias) ),  colsum[i] = sum_o W[o,i]
// Two plain kernels (kernel boundary = cheapest grid-wide sync on CDNA4;
// measured: hand-rolled barrier ~80us, coop grid.sync ~25-30us, boundary ~3us).
//   K1: partial[g][c] = sum of W rows [256g,256g+256) (8 groups x 64 slices,
//       512 blocks x 512 thr). Block 0 also writes bsum = sum(bias).
//   K2: 1024 blocks x 512 thr, __launch_bounds__(512,8) -> VGPR<=64,
//       4 blocks/CU co-resident = 8 waves/SIMD. Each wave owns ONE x row,
//       prefetched into 8xfloat4 regs while partial[8][2048] (L2-hot) is
//       accumulated in-place into LDS; then pure LDS+FMA dot product.

constexpr int IN_DIM  = 2048;
constexpr int BATCH   = 8192;
constexpr float SCALE2 = 0.01f;   // SCALE*SCALE
constexpr int DGROUPS = 8;        // partial depth (256 rows each)

// ---------------------------------------------------------------------------
// K1: 512 blocks x 512 threads (round-8 proven). Block b: row-group g = b>>6
// (256 rows), col-slice h = b&63 (32 cols = 8 float4). Thread t: col4 =
// h*8 + (t&7), rsub = t>>3, rows g*256 + rsub + 64k, k = 0..3.
// Coalescing: 8 lanes x 16B = 128B contiguous per row segment.
// ---------------------------------------------------------------------------
__global__ __launch_bounds__(512)
void colsum_partial(const float* __restrict__ W, const float* __restrict__ bias,
                    float* __restrict__ partial, float* __restrict__ bsum) {
    const int t = threadIdx.x;          // 0..511
    const int b = blockIdx.x;           // 0..511
    const int g = b >> 6;               // 0..7
    const int h = b & 63;               // 0..63
    const int lane = t & 63, w = t >> 6;

    const float4* W4 = reinterpret_cast<const float4*>(W);
    const int c4   = (h << 3) + (t & 7);           // float4 col 0..511
    const int rsub = t >> 3;                       // 0..63
    const size_t base = (size_t)((g << 8) + rsub) * (IN_DIM / 4) + c4;

    float4 acc = {0.f, 0.f, 0.f, 0.f};
    #pragma unroll
    for (int k = 0; k < 4; ++k) {
        const float4 v = W4[base + (size_t)(k << 6) * (IN_DIM / 4)];
        acc.x += v.x; acc.y += v.y; acc.z += v.z; acc.w += v.w;
    }
    // merge rsub bits within the wave (lane bits 3,4,5); c4 invariant
    #pragma unroll
    for (int m = 8; m <= 32; m <<= 1) {
        acc.x += __shfl_xor(acc.x, m); acc.y += __shfl_xor(acc.y, m);
        acc.z += __shfl_xor(acc.z, m); acc.w += __shfl_xor(acc.w, m);
    }

    __shared__ float4 redA[8][8];       // [wave][col4 within slice]
    if (lane < 8) redA[w][lane] = acc;
    __syncthreads();
    if (t < 8) {                        // one thread per col4 of this slice
        float4 s = redA[0][t];
        #pragma unroll
        for (int j = 1; j < 8; ++j) {
            const float4 v = redA[j][t];
            s.x += v.x; s.y += v.y; s.z += v.z; s.w += v.w;
        }
        reinterpret_cast<float4*>(partial)[(size_t)g * (IN_DIM / 4) + (h << 3) + t] = s;
    }

    if (b == 0) {  // bias sum (concurrent with the rest)
        __shared__ float bs_red[8];
        float s = 0.f;
        #pragma unroll
        for (int k = 0; k < 4; ++k) s += bias[t + (k << 9)];
        #pragma unroll
        for (int off = 32; off; off >>= 1) s += __shfl_down(s, off);
        if (lane == 0) bs_red[w] = s;
        __syncthreads();
        if (t == 0) {
            float tot = 0.f;
            #pragma unroll
            for (int j = 0; j < 8; ++j) tot += bs_red[j];
            bsum[0] = tot;
        }
    }
}

// ---------------------------------------------------------------------------
// K2: 1024 blocks x 512 threads, VGPR capped at 64 -> 4 blocks/CU resident
// = 32 waves/CU = 8 waves/SIMD. Wave w owns row b*8 + w (prefetched into
// regs); partial is accumulated in-place (few live regs) into LDS wsum.
// ---------------------------------------------------------------------------
__global__ __launch_bounds__(512, 8)
void reduce_matvec(const float* __restrict__ x, const float* __restrict__ partial,
                   const float* __restrict__ bsum, float* __restrict__ out) {
    __shared__ float4 wsh4[IN_DIM / 4];   // 8 KB
    __shared__ float  bs_sh;

    const int t    = threadIdx.x;          // 0..511
    const int b    = blockIdx.x;           // 0..1023
    const int lane = t & 63;
    const int w    = t >> 6;               // 0..7

    // ---- issue this wave's x-row prefetch first (HBM, longest latency)
    const float4* x4 = reinterpret_cast<const float4*>(x);
    const int row = (b << 3) + w;
    const size_t xb = (size_t)row * (IN_DIM / 4);
    float4 xv[8];
    #pragma unroll
    for (int k = 0; k < 8; ++k)
        xv[k] = x4[xb + (k << 6) + lane];

    if (t == 0) bs_sh = bsum[0];

    // ---- accumulate partial[8][2048] (L2-hot) in-place into LDS
    const float4* p4 = reinterpret_cast<const float4*>(partial);
    float4 s = p4[t];
    #pragma unroll 2
    for (int g = 1; g < DGROUPS; ++g) {
        const float4 v = p4[(size_t)g * (IN_DIM / 4) + t];
        s.x += v.x; s.y += v.y; s.z += v.z; s.w += v.w;
    }
    wsh4[t] = s;
    __syncthreads();

    // ---- dot(x_row, wsum): pure LDS + FMA, x already in regs
    float a0 = 0.f;
    #pragma unroll
    for (int k = 0; k < 8; ++k) {
        const float4 wv = wsh4[(k << 6) + lane];
        a0 += xv[k].x * wv.x + xv[k].y * wv.y + xv[k].z * wv.z + xv[k].w * wv.w;
    }
    #pragma unroll
    for (int off = 32; off; off >>= 1)
        a0 += __shfl_down(a0, off);
    if (lane == 0)
        out[row] = SCALE2 * (a0 + bs_sh);
}

extern "C" void kernel_launch(void* const* d_in, const int* in_sizes, int n_in,
                              void* d_out, int out_size, void* d_ws, size_t ws_size,
                              hipStream_t stream) {
    const float* x    = (const float*)d_in[0];   // [8192, 2048]
    const float* W    = (const float*)d_in[1];   // [2048, 2048]
    const float* bias = (const float*)d_in[2];   // [2048]
    float* out = (float*)d_out;                  // [8192]
    char*  ws  = (char*)d_ws;

    // ws layout: partial[8][2048] (64 KB) | bsum (64 B)
    float* partial = (float*)ws;
    float* bsum    = (float*)(ws + (size_t)DGROUPS * IN_DIM * sizeof(float));

    colsum_partial<<<512, 512, 0, stream>>>(W, bias, partial, bsum);
    reduce_matvec<<<BATCH / 8, 512, 0, stream>>>(x, partial, bsum, out);
}

// Round 13
// 21.649 us; speedup vs baseline: 1.0224x; 1.0224x over previous
//
#include <hip/hip_runtime.h>

// out[b] = SCALE^2 * ( dot(x[b,:], colsum) + sum(bias) ),  colsum[i] = sum_o W[o,i]
// Collapses the GEMM (y = x W^T + b; out = 0.01 * y.sum(-1)) via reassociation.
//
// Two plain kernels — measured to be the optimal structure on MI355X:
//   grid-wide sync cost ledger (this session): hand-rolled barrier ~80us+,
//   cooperative grid.sync ~25-30us (and rejected by graph capture),
//   kernel boundary ~3us  -> two nodes, boundary as the sync.
//   K1: partial[g][c] = sum of W rows [256g,256g+256) (8 groups x 64 slices,
//       512 blocks x 512 thr, 2 blocks/CU). Block 0 also sums bias.
//   K2: 512 blocks x 512 thr (4 waves/SIMD — measured saturation point;
//       8 waves/SIMD regressed). Per block: reduce partial[8][2048] (L2-hot)
//       into LDS wsum, with row-0 x loads prefetched into regs BEFORE the
//       barrier so phase 1 hides their latency; then 2-row matvec per wave
//       (row 0 from regs, row 1 streamed), shuffle-reduced.

constexpr int IN_DIM  = 2048;
constexpr int BATCH   = 8192;
constexpr float SCALE2 = 0.01f;   // SCALE*SCALE
constexpr int DGROUPS = 8;        // partial depth (256 rows each)

// ---------------------------------------------------------------------------
// K1: 512 blocks x 512 threads. Block b: row-group g = b>>6 (256 rows),
// col-slice h = b&63 (32 cols = 8 float4). Thread t: col4 = h*8 + (t&7),
// rsub = t>>3 (0..63), rows g*256 + rsub + 64k, k = 0..3.
// Coalescing: 8 lanes x 16B = 128B contiguous per row segment.
// ---------------------------------------------------------------------------
__global__ __launch_bounds__(512)
void colsum_partial(const float* __restrict__ W, const float* __restrict__ bias,
                    float* __restrict__ partial, float* __restrict__ bsum) {
    const int t = threadIdx.x;          // 0..511
    const int b = blockIdx.x;           // 0..511
    const int g = b >> 6;               // 0..7
    const int h = b & 63;               // 0..63
    const int lane = t & 63, w = t >> 6;

    const float4* W4 = reinterpret_cast<const float4*>(W);
    const int c4   = (h << 3) + (t & 7);           // float4 col 0..511
    const int rsub = t >> 3;                       // 0..63
    const size_t base = (size_t)((g << 8) + rsub) * (IN_DIM / 4) + c4;

    float4 acc = {0.f, 0.f, 0.f, 0.f};
    #pragma unroll
    for (int k = 0; k < 4; ++k) {
        const float4 v = W4[base + (size_t)(k << 6) * (IN_DIM / 4)];
        acc.x += v.x; acc.y += v.y; acc.z += v.z; acc.w += v.w;
    }
    // merge rsub bits within the wave (lane bits 3,4,5); c4 invariant
    #pragma unroll
    for (int m = 8; m <= 32; m <<= 1) {
        acc.x += __shfl_xor(acc.x, m); acc.y += __shfl_xor(acc.y, m);
        acc.z += __shfl_xor(acc.z, m); acc.w += __shfl_xor(acc.w, m);
    }

    __shared__ float4 redA[8][8];       // [wave][col4 within slice]
    if (lane < 8) redA[w][lane] = acc;
    __syncthreads();
    if (t < 8) {                        // one thread per col4 of this slice
        float4 s = redA[0][t];
        #pragma unroll
        for (int j = 1; j < 8; ++j) {
            const float4 v = redA[j][t];
            s.x += v.x; s.y += v.y; s.z += v.z; s.w += v.w;
        }
        reinterpret_cast<float4*>(partial)[(size_t)g * (IN_DIM / 4) + (h << 3) + t] = s;
    }

    if (b == 0) {  // bias sum (concurrent with the rest)
        __shared__ float bs_red[8];
        float s = 0.f;
        #pragma unroll
        for (int k = 0; k < 4; ++k) s += bias[t + (k << 9)];
        #pragma unroll
        for (int off = 32; off; off >>= 1) s += __shfl_down(s, off);
        if (lane == 0) bs_red[w] = s;
        __syncthreads();
        if (t == 0) {
            float tot = 0.f;
            #pragma unroll
            for (int j = 0; j < 8; ++j) tot += bs_red[j];
            bsum[0] = tot;
        }
    }
}

// ---------------------------------------------------------------------------
// K2: 512 blocks x 512 threads (8 waves, 2 blocks/CU -> 4 waves/SIMD).
// Prefetch: issue partial loads AND row-0 x loads before the barrier so the
// LDS round-trip + barrier hide the first global-load latency.
// Phase 2: matvec rows [16b, 16b+16); wave w rows 16b+2w (prefetched), +1.
// ---------------------------------------------------------------------------
__global__ __launch_bounds__(512)
void reduce_matvec(const float* __restrict__ x, const float* __restrict__ partial,
                   const float* __restrict__ bsum, float* __restrict__ out) {
    __shared__ float4 wsh4[IN_DIM / 4];   // 8 KB
    __shared__ float  bs_sh;

    const int t    = threadIdx.x;          // 0..511
    const int b    = blockIdx.x;           // 0..511
    const int lane = t & 63;
    const int w    = t >> 6;               // 0..7

    // ---- issue phase-1 loads (partial[8][2048], L2-hot)
    const float4* p4 = reinterpret_cast<const float4*>(partial);
    float4 pv[DGROUPS];
    #pragma unroll
    for (int g = 0; g < DGROUPS; ++g)
        pv[g] = p4[(size_t)g * (IN_DIM / 4) + t];

    // ---- issue row-0 x loads (independent of LDS wsum)
    const float4* x4 = reinterpret_cast<const float4*>(x);
    const int r0 = (b << 4) + (w << 1);
    const size_t xb = (size_t)r0 * (IN_DIM / 4);
    float4 xv[8];
    #pragma unroll
    for (int k = 0; k < 8; ++k)
        xv[k] = x4[xb + (k << 6) + lane];

    if (t == 0) bs_sh = bsum[0];

    // ---- reduce partials into LDS wsum
    float4 acc = pv[0];
    #pragma unroll
    for (int g = 1; g < DGROUPS; ++g) {
        acc.x += pv[g].x; acc.y += pv[g].y;
        acc.z += pv[g].z; acc.w += pv[g].w;
    }
    wsh4[t] = acc;
    __syncthreads();

    // ---- phase 2: row 0 from prefetched regs, row 1 streamed in-loop
    float a0 = 0.f, a1 = 0.f;
    #pragma unroll
    for (int k = 0; k < 8; ++k) {
        const int ci = (k << 6) + lane;
        const float4 wv = wsh4[ci];
        const float4 v1 = x4[xb + 512 + ci];
        a0 += xv[k].x * wv.x + xv[k].y * wv.y + xv[k].z * wv.z + xv[k].w * wv.w;
        a1 += v1.x * wv.x + v1.y * wv.y + v1.z * wv.z + v1.w * wv.w;
    }
    #pragma unroll
    for (int off = 32; off; off >>= 1) {
        a0 += __shfl_down(a0, off);
        a1 += __shfl_down(a1, off);
    }
    if (lane == 0) {
        const float bs = bs_sh;
        *reinterpret_cast<float2*>(out + r0) =
            make_float2(SCALE2 * (a0 + bs), SCALE2 * (a1 + bs));
    }
}

extern "C" void kernel_launch(void* const* d_in, const int* in_sizes, int n_in,
                              void* d_out, int out_size, void* d_ws, size_t ws_size,
                              hipStream_t stream) {
    const float* x    = (const float*)d_in[0];   // [8192, 2048]
    const float* W    = (const float*)d_in[1];   // [2048, 2048]
    const float* bias = (const float*)d_in[2];   // [2048]
    float* out = (float*)d_out;                  // [8192]
    char*  ws  = (char*)d_ws;

    // ws layout: partial[8][2048] (64 KB) | bsum (64 B)
    float* partial = (float*)ws;
    float* bsum    = (float*)(ws + (size_t)DGROUPS * IN_DIM * sizeof(float));

    colsum_partial<<<512, 512, 0, stream>>>(W, bias, partial, bsum);
    reduce_matvec<<<BATCH / 16, 512, 0, stream>>>(x, partial, bsum, out);
}